// Round 18
// baseline (771.598 us; speedup 1.0000x reference)
//
#include <hip/hip_runtime.h>
#include <hip/hip_bf16.h>
#include <cstdint>

#define NN 1000000
#define DD 128
#define BB 4096
#define S1C 25
#define S2C 10
#define MM 45056   // BB * (1 + S2C)

using f32x4  = __attribute__((ext_vector_type(4))) float;
using s16x8  = __attribute__((ext_vector_type(8))) short;
using u16x8  = __attribute__((ext_vector_type(8))) unsigned short;

__device__ __forceinline__ ushort f2bf(float x) {
    uint32_t u = __float_as_uint(x);
    u += 0x7fff + ((u >> 16) & 1);      // round-to-nearest-even
    return (ushort)(u >> 16);
}
__device__ __forceinline__ float bf2f(ushort h) {
    return __uint_as_float(((uint32_t)h) << 16);
}

// ---------------- Kernel 0: stream-convert Z fp32 [NN][128] -> Zb bf16 (256 MB)
// 768 MB total traffic, pure streaming. Bounded grid-stride loop over
// NN*DD/8 = 16,000,000 groups of 8 floats (R8 bug: fixed trip count overran Z).
__global__ __launch_bounds__(256) void k_conv(
    const float* __restrict__ Z, ushort* __restrict__ Zb)
{
    const size_t stride = (size_t)2048 * 256;
    const size_t G = (size_t)NN * DD / 8;   // 16,000,000
    for (size_t g = (size_t)blockIdx.x * 256 + threadIdx.x; g < G; g += stride) {
        f32x4 a = ((const f32x4*)Z)[g * 2];
        f32x4 b = ((const f32x4*)Z)[g * 2 + 1];
        u16x8 o;
        o[0] = f2bf(a.x); o[1] = f2bf(a.y); o[2] = f2bf(a.z); o[3] = f2bf(a.w);
        o[4] = f2bf(b.x); o[5] = f2bf(b.y); o[6] = f2bf(b.z); o[7] = f2bf(b.w);
        ((u16x8*)Zb)[g] = o;
    }
}

// ---------------- Kernel A: layer-1 gather + neighbor mean from bf16 Zb -> cat1 (bf16 [MM][256])
// One wave per node. Row = 256 B = 16 lanes x 16 B; each wave-load covers 4 rows
// (quarter qt = lane>>4 picks the row). 7 row-loads + 1 index load per wave.
__global__ __launch_bounds__(256) void k_gather1(
    const ushort* __restrict__ Zb, const int* __restrict__ node_idx,
    const int* __restrict__ nbr1, ushort* __restrict__ cat1)
{
    const int lane = threadIdx.x & 63;
    const int qt   = lane >> 4;          // quarter 0..3 -> row within a 4-row load
    const int c16  = lane & 15;          // 16-B chunk within the 256-B row
    const int m = blockIdx.x * 4 + (threadIdx.x >> 6);

    const int nbv  = nbr1[(size_t)m * S1C + (lane < S1C ? lane : S1C - 1)];
    const int self = node_idx[m];

    float facc[8] = {};
    #pragma unroll
    for (int j = 0; j < 6; ++j) {                    // neighbors 0..23
        const int idx = __shfl(nbv, 4 * j + qt, 64);
        const u16x8 d = *(const u16x8*)(Zb + (size_t)idx * DD + c16 * 8);
        #pragma unroll
        for (int e = 0; e < 8; ++e) facc[e] += bf2f(d[e]);
    }
    // load 7: qt0 -> self row (passthrough), qt1 -> neighbor 24, qt2/3 duplicate nbr24 (masked)
    const int idx24 = __shfl(nbv, S1C - 1, 64);
    const int base7 = (qt == 0) ? self : idx24;
    const u16x8 d7  = *(const u16x8*)(Zb + (size_t)base7 * DD + c16 * 8);
    if (qt == 1) {
        #pragma unroll
        for (int e = 0; e < 8; ++e) facc[e] += bf2f(d7[e]);
    }

    // reduce across the 4 quarters (lanes {l, l^16, l^32, l^48} share c16)
    #pragma unroll
    for (int e = 0; e < 8; ++e) {
        facc[e] += __shfl_xor(facc[e], 16, 64);
        facc[e] += __shfl_xor(facc[e], 32, 64);
    }

    if (qt == 0) {
        const float inv = 1.0f / S1C;
        u16x8 mv;
        #pragma unroll
        for (int e = 0; e < 8; ++e) mv[e] = f2bf(facc[e] * inv);
        ushort* crow = cat1 + (size_t)m * 256;
        *(u16x8*)(crow + c16 * 8)       = d7;   // h_self (bf16 passthrough) -> cols [0,128)
        *(u16x8*)(crow + 128 + c16 * 8) = mv;   // mean                      -> cols [128,256)
    }
}

// ---------------- Kernel C: layer-2 gather over h1 (bf16 [MM][128]) -> cat2 (bf16 [BB][256])
__global__ __launch_bounds__(256) void k_gather2(
    const ushort* __restrict__ h1, const int* __restrict__ nbr2,
    ushort* __restrict__ cat2)
{
    const int lane = threadIdx.x & 63;
    const int half = lane >> 5;
    const int c    = lane & 31;          // covers 4 bf16
    const int b = blockIdx.x * 4 + (threadIdx.x >> 6);

    const int nbv = nbr2[(size_t)b * S2C + (lane < S2C ? lane : S2C - 1)];

    float a0 = 0.f, a1 = 0.f, a2 = 0.f, a3 = 0.f;
    #pragma unroll
    for (int j = 0; j < 5; ++j) {
        const int idx = __shfl(nbv, 2 * j + half, 64);
        const uint2 v = *(const uint2*)(h1 + (size_t)idx * DD + c * 4);
        a0 += bf2f((ushort)(v.x & 0xffffu));
        a1 += bf2f((ushort)(v.x >> 16));
        a2 += bf2f((ushort)(v.y & 0xffffu));
        a3 += bf2f((ushort)(v.y >> 16));
    }
    const uint2 sv = *(const uint2*)(h1 + (size_t)b * DD + c * 4);

    float t0 = a0 + __shfl_xor(a0, 32, 64);
    float t1 = a1 + __shfl_xor(a1, 32, 64);
    float t2 = a2 + __shfl_xor(a2, 32, 64);
    float t3 = a3 + __shfl_xor(a3, 32, 64);

    if (half == 0) {
        const float inv = 1.0f / S2C;
        ushort4 om;
        om.x = f2bf(t0 * inv); om.y = f2bf(t1 * inv);
        om.z = f2bf(t2 * inv); om.w = f2bf(t3 * inv);
        ushort* crow = cat2 + (size_t)b * 256;
        *(uint2*)(crow + c * 4)           = sv;  // self bf16 passthrough
        *(ushort4*)(crow + 128 + c * 4)   = om;  // mean
    }
}

// ---------------- GEMM + sigmoid + L2-normalize (unchanged).
template<int OUT_BF16>
__global__ __launch_bounds__(256) void k_sage(
    const ushort* __restrict__ cat, const float* __restrict__ W,
    void* __restrict__ out)
{
    __shared__ ushort Wl[128][256];   // 64 KB, swizzled
    const int tid = threadIdx.x;
    #pragma unroll
    for (int it = 0; it < 32; ++it) {
        int i = it * 256 + tid;               // float4 index into W
        float4 w = ((const float4*)W)[i];
        int e = i << 2;
        int r = e >> 8, c = e & 255;
        int cs = c ^ ((r & 7) << 3);          // swizzle (moves 8-elem blocks; c%4 preserved)
        ushort4 o;
        o.x = f2bf(w.x); o.y = f2bf(w.y); o.z = f2bf(w.z); o.w = f2bf(w.w);
        *(ushort4*)&Wl[r][cs] = o;
    }
    __syncthreads();

    const int lane = tid & 63;
    const int q = lane >> 4;
    const int p = lane & 15;
    const int row0 = blockIdx.x * 64 + (tid >> 6) * 16;

    const ushort* arow = cat + (size_t)(row0 + p) * 256 + q * 8;
    f32x4 acc[8] = {};
    #pragma unroll
    for (int ks = 0; ks < 8; ++ks) {
        s16x8 a = *(const s16x8*)(arow + ks * 32);
        #pragma unroll
        for (int t = 0; t < 8; ++t) {
            const int d = t * 16 + p;
            const int kcol = (ks * 32 + q * 8) ^ ((d & 7) << 3);
            s16x8 b = *(const s16x8*)&Wl[d][kcol];
            acc[t] = __builtin_amdgcn_mfma_f32_16x16x32_bf16(a, b, acc[t], 0, 0, 0);
        }
    }

    float z[8][4];
    float ss[4] = {0.f, 0.f, 0.f, 0.f};
    #pragma unroll
    for (int t = 0; t < 8; ++t)
        #pragma unroll
        for (int r = 0; r < 4; ++r) {
            float v = 1.0f / (1.0f + __expf(-acc[t][r]));
            z[t][r] = v;
            ss[r] += v * v;
        }
    #pragma unroll
    for (int r = 0; r < 4; ++r) {
        float s = ss[r];
        s += __shfl_xor(s, 1);
        s += __shfl_xor(s, 2);
        s += __shfl_xor(s, 4);
        s += __shfl_xor(s, 8);
        ss[r] = rsqrtf(s);
    }
    #pragma unroll
    for (int t = 0; t < 8; ++t)
        #pragma unroll
        for (int r = 0; r < 4; ++r) {
            int row = row0 + q * 4 + r;
            int col = t * 16 + p;
            float v = z[t][r] * ss[r];
            if (OUT_BF16) ((ushort*)out)[(size_t)row * DD + col] = f2bf(v);
            else          ((float*)out)[(size_t)row * DD + col]  = v;
        }
}

extern "C" void kernel_launch(void* const* d_in, const int* in_sizes, int n_in,
                              void* d_out, int out_size, void* d_ws, size_t ws_size,
                              hipStream_t stream)
{
    const float* Z        = (const float*)d_in[0];
    const float* W1       = (const float*)d_in[1];
    const float* W2       = (const float*)d_in[2];
    const int*   node_idx = (const int*)d_in[3];
    const int*   nbr1     = (const int*)d_in[4];
    const int*   nbr2     = (const int*)d_in[5];

    // ws layout (bf16): Zb [NN][128] (256 MB) | cat1 [MM][256] | h1 [MM][128] | cat2 [BB][256]
    ushort* Zb   = (ushort*)d_ws;
    ushort* cat1 = Zb   + (size_t)NN * DD;
    ushort* h1   = cat1 + (size_t)MM * 256;
    ushort* cat2 = h1   + (size_t)MM * DD;

    k_conv<<<2048, 256, 0, stream>>>(Z, Zb);
    k_gather1<<<MM / 4, 256, 0, stream>>>(Zb, node_idx, nbr1, cat1);
    k_sage<1><<<MM / 64, 256, 0, stream>>>(cat1, W1, (void*)h1);
    k_gather2<<<BB / 4, 256, 0, stream>>>(h1, nbr2, cat2);
    k_sage<0><<<BB / 64, 256, 0, stream>>>(cat2, W2, d_out);
}